// Round 4
// baseline (401.430 us; speedup 1.0000x reference)
//
#include <hip/hip_runtime.h>

// SGP spatial encoder: out[n] = concat(x, A x, A^2 x, A^3 x, mean(x)) with
// A = D^-1/2 W D^-1/2 (in-degree at col/target).
// R6: prop chunk-8 edge loop -> 8 gathers in flight.
// R7/R8 FAILED (cnt padding, atomic MLP) => k_build was device-atomic
//   THROUGHPUT bound; R9 bucket partition fixed it (65k atomics): 315->284us.
// R10: props = 216us = 76% of runtime. Gather rate stuck at ~5 B/cyc/CU across
// all MLP variants => per-CU outstanding-line cap (~40) x latency model:
// 12.8MB table > 4MB per-XCD L2 -> ~31% L2 hit -> ~480cy avg latency.
// Fix: split hops 2,3 into 4 column-pass kernels each; per-pass gather table
// = N x 64B = 3.2MB < 4MB -> L2-resident -> ~200cy -> ~2x gather rate.
// nt loads on slot stream + nt stores on outputs protect residency.
// Hop1 untouched (fp32-norm numerics preserved; absmax must stay 0.0078125).

#define D 128
#define OUTC4 160   // float4s per output row
#define CAP 64      // slots per node; Poisson(16) => overflow ~impossible (guarded)
#define CH 8        // edge chunk = gathers in flight per thread (prop)
#define PB 256      // partition blocks = coarse buckets
#define CB 512      // colsum blocks
#define BCAP 5120   // bucket capacity (mean 4096, 16 sigma headroom; guarded)

typedef float f4v __attribute__((ext_vector_type(4)));
typedef unsigned u4v __attribute__((ext_vector_type(4)));

__device__ inline void nt_store_f4(float4* p, float4 v) {
    f4v t = {v.x, v.y, v.z, v.w};
    __builtin_nontemporal_store(t, (f4v*)p);
}
__device__ inline void nt_store_u4(uint4* p, uint4 v) {
    u4v t = {v.x, v.y, v.z, v.w};
    __builtin_nontemporal_store(t, (u4v*)p);
}

__device__ inline unsigned short f2bf(float f) {
    unsigned u = __float_as_uint(f);
    u += 0x7FFFu + ((u >> 16) & 1u);   // round-nearest-even
    return (unsigned short)(u >> 16);
}
__device__ inline float bfhi(unsigned u) {           // bf16 in high half
    return __uint_as_float(u & 0xFFFF0000u);
}
__device__ inline float bflo(unsigned u) {           // bf16 in low half
    return __uint_as_float(u << 16);
}
__device__ inline unsigned pack2(float lo, float hi) {
    return ((unsigned)f2bf(hi) << 16) | (unsigned)f2bf(lo);
}
__device__ inline void fma8(float4& a0, float4& a1, float w, uint4 v) {
    a0.x += w * bflo(v.x); a0.y += w * bfhi(v.x);
    a0.z += w * bflo(v.y); a0.w += w * bfhi(v.y);
    a1.x += w * bflo(v.z); a1.y += w * bfhi(v.z);
    a1.z += w * bflo(v.w); a1.w += w * bfhi(v.w);
}

// blocks [0,PB): partition edges into coarse buckets. blocks [PB,PB+CB): x colsum.
__global__ void k_part(const int* __restrict__ row, const int* __restrict__ col,
                       const float* __restrict__ ew, const float* __restrict__ x,
                       int* __restrict__ bcur, uint2* __restrict__ breg,
                       float* __restrict__ gsum, int E, int N) {
    __shared__ int shi[512];   // [0,256)=hist/cursor, [256,512)=chunk base; colsum aliases float
    if ((int)blockIdx.x < PB) {
        int* hist = shi;
        int* base = shi + 256;
        int rng = (E + PB - 1) / PB;
        int e0 = blockIdx.x * rng;
        int e1 = e0 + rng; if (e1 > E) e1 = E;
        hist[threadIdx.x] = 0;
        __syncthreads();
        for (int e = e0 + (int)threadIdx.x; e < e1; e += 256)
            atomicAdd(&hist[(unsigned)col[e] >> 8], 1);
        __syncthreads();
        int h = hist[threadIdx.x];
        if (h) base[threadIdx.x] = atomicAdd(&bcur[threadIdx.x], h);
        __syncthreads();
        hist[threadIdx.x] = 0;   // reuse as block-local cursor
        __syncthreads();
        for (int e = e0 + (int)threadIdx.x; e < e1; e += 256) {
            int c = col[e];
            int b = (unsigned)c >> 8;
            int r = atomicAdd(&hist[b], 1);
            int pos = base[b] + r;
            if (pos < BCAP)
                breg[(size_t)b * BCAP + pos] =
                    make_uint2(((unsigned)f2bf(ew[e]) << 16) | (unsigned)row[e], (unsigned)c);
        }
    } else {
        float* sh = (float*)shi;
        int bid = blockIdx.x - PB;        // 0..CB-1
        int f = threadIdx.x & 127;
        int sub = threadIdx.x >> 7;       // 0/1
        float acc = 0.f;
        for (int n = bid * 2 + sub; n < N; n += CB * 2)
            acc += x[(size_t)n * D + f];
        if (sub) sh[f] = acc;
        __syncthreads();
        if (!sub) atomicAdd(&gsum[f], acc + sh[f]);
    }
}

// blocks [0,GB): group bucket -> slots, cnt, dinv (LDS atomics only).
// blocks [GB,...): init (x copy / mean broadcast / bf16 staging).
__global__ void k_prep(const int* __restrict__ bcur, const uint2* __restrict__ breg,
                       int* __restrict__ cnt, float* __restrict__ dinv,
                       unsigned* __restrict__ slots, const float4* __restrict__ x4,
                       const float* __restrict__ gsum, float4* __restrict__ out4,
                       uint4* __restrict__ xb0, int N, int GB, float invN) {
    __shared__ int shi[512];   // [0,256)=ncur, [256,512)=wsum(float)
    if ((int)blockIdx.x < GB) {
        int* ncur = shi;
        float* wsum = (float*)(shi + 256);
        int b = blockIdx.x;
        ncur[threadIdx.x] = 0;
        wsum[threadIdx.x] = 0.f;
        __syncthreads();
        int cb = bcur[b]; if (cb > BCAP) cb = BCAP;
        const uint2* br = breg + (size_t)b * BCAP;
        for (int i = threadIdx.x; i < cb; i += 256) {
            uint2 ed = br[i];
            int node = (int)ed.y;
            int l = node & 255;
            int r = atomicAdd(&ncur[l], 1);
            if (r < CAP) slots[(size_t)node * CAP + r] = ed.x;
            atomicAdd(&wsum[l], bfhi(ed.x));
        }
        __syncthreads();
        int node = b * 256 + (int)threadIdx.x;
        if (node < N) {
            cnt[node] = ncur[threadIdx.x];
            float v = wsum[threadIdx.x];
            dinv[node] = v > 0.f ? rsqrtf(v) : 0.f;
        }
    } else {
        int t = (blockIdx.x - GB) * 256 + threadIdx.x;
        if (t >= N * 16) return;
        int n = t >> 4;
        int q = t & 15;
        float4 v0 = x4[(size_t)n * 32 + 2 * q];
        float4 v1 = x4[(size_t)n * 32 + 2 * q + 1];
        size_t ob = (size_t)n * OUTC4;
        nt_store_f4(&out4[ob + 2 * q], v0);
        nt_store_f4(&out4[ob + 2 * q + 1], v1);
        nt_store_u4(&xb0[(size_t)n * 16 + q],
                    make_uint4(pack2(v0.x, v0.y), pack2(v0.z, v0.w),
                               pack2(v1.x, v1.y), pack2(v1.z, v1.w)));
        int g = 8 * q;
        nt_store_f4(&out4[ob + 128 + 2 * q],
                    make_float4(gsum[g] * invN, gsum[g + 1] * invN,
                                gsum[g + 2] * invN, gsum[g + 3] * invN));
        nt_store_f4(&out4[ob + 129 + 2 * q],
                    make_float4(gsum[g + 4] * invN, gsum[g + 5] * invN,
                                gsum[g + 6] * invN, gsum[g + 7] * invN));
    }
}

// hop1 pull: 16 lanes/node, lane owns 8 bf16 columns; fp32 norm
// w = dinv[dst]*ew*dinv[src]; slot rewritten as bf16(w). (unchanged numerics)
__global__ void k_prop1(const int* __restrict__ cnt, unsigned* __restrict__ slots,
                        const float* __restrict__ dinv, const uint4* __restrict__ xin,
                        float4* __restrict__ out4, uint4* __restrict__ xout,
                        int N, int out_off4) {
    int t = blockIdx.x * blockDim.x + threadIdx.x;
    int node = t >> 4;
    if (node >= N) return;
    int lane = t & 15;
    int c = cnt[node]; if (c > CAP) c = CAP;
    unsigned* s = slots + (size_t)node * CAP;
    float dd = dinv[node];
    float4 a0 = make_float4(0.f, 0.f, 0.f, 0.f);
    float4 a1 = make_float4(0.f, 0.f, 0.f, 0.f);
    int i = 0;
    for (; i + CH <= c; i += CH) {
        unsigned sl[CH]; float w[CH]; uint4 v[CH];
#pragma unroll
        for (int j = 0; j < CH; j++) sl[j] = s[i + j];
#pragma unroll
        for (int j = 0; j < CH; j++)
            w[j] = dd * bfhi(sl[j]) * dinv[sl[j] & 0xFFFFu];
        if (lane == 0) {
#pragma unroll
            for (int j = 0; j < CH; j++)
                s[i + j] = ((unsigned)f2bf(w[j]) << 16) | (sl[j] & 0xFFFFu);
        }
#pragma unroll
        for (int j = 0; j < CH; j++) v[j] = xin[(size_t)(sl[j] & 0xFFFFu) * 16 + lane];
#pragma unroll
        for (int j = 0; j < CH; j++) fma8(a0, a1, w[j], v[j]);
    }
    if (i < c) {  // predicated tail chunk; clamped dup addresses are cache-hits
        unsigned sl[CH]; float w[CH]; uint4 v[CH];
#pragma unroll
        for (int j = 0; j < CH; j++) {
            int idx = (i + j < c) ? i + j : c - 1;
            sl[j] = s[idx];
        }
#pragma unroll
        for (int j = 0; j < CH; j++) {
            float ww = dd * bfhi(sl[j]) * dinv[sl[j] & 0xFFFFu];
            w[j] = (i + j < c) ? ww : 0.f;
        }
        if (lane == 0) {
#pragma unroll
            for (int j = 0; j < CH; j++)
                if (i + j < c) s[i + j] = ((unsigned)f2bf(w[j]) << 16) | (sl[j] & 0xFFFFu);
        }
#pragma unroll
        for (int j = 0; j < CH; j++) v[j] = xin[(size_t)(sl[j] & 0xFFFFu) * 16 + lane];
#pragma unroll
        for (int j = 0; j < CH; j++) fma8(a0, a1, w[j], v[j]);
    }
    size_t ob = (size_t)node * OUTC4 + out_off4 + 2 * lane;
    nt_store_f4(&out4[ob], a0);
    nt_store_f4(&out4[ob + 1], a1);
    nt_store_u4(&xout[(size_t)node * 16 + lane],
                make_uint4(pack2(a0.x, a0.y), pack2(a0.z, a0.w),
                           pack2(a1.x, a1.y), pack2(a1.z, a1.w)));
}

// hops 2,3 column-pass: 4 lanes/node, lane owns 8 bf16 cols of a 32-col group.
// Gather table per pass = N x 64B = 3.2MB -> per-XCD-L2-resident.
// Slot stream nt (no L2 allocate); all stores nt. Per-column edge order
// identical to the full-row kernel -> bit-exact.
__global__ void k_pass(const int* __restrict__ cnt, const unsigned* __restrict__ slots,
                       const uint4* __restrict__ xin, float4* __restrict__ out4,
                       uint4* __restrict__ xout, int N, int out_off4, int pass,
                       int writeb) {
    int t = blockIdx.x * blockDim.x + threadIdx.x;
    int node = t >> 2;
    if (node >= N) return;
    int lane = t & 3;
    int c = cnt[node]; if (c > CAP) c = CAP;
    const unsigned* s = slots + (size_t)node * CAP;
    const uint4* xp = xin + 4 * pass + lane;
    float4 a0 = make_float4(0.f, 0.f, 0.f, 0.f);
    float4 a1 = make_float4(0.f, 0.f, 0.f, 0.f);
    int i = 0;
    for (; i + CH <= c; i += CH) {
        unsigned sl[CH]; uint4 v[CH];
#pragma unroll
        for (int j = 0; j < CH; j++) sl[j] = __builtin_nontemporal_load(&s[i + j]);
#pragma unroll
        for (int j = 0; j < CH; j++) v[j] = xp[(size_t)(sl[j] & 0xFFFFu) * 16];
#pragma unroll
        for (int j = 0; j < CH; j++) fma8(a0, a1, bfhi(sl[j]), v[j]);
    }
    if (i < c) {
        unsigned sl[CH]; float w[CH]; uint4 v[CH];
#pragma unroll
        for (int j = 0; j < CH; j++) {
            int idx = (i + j < c) ? i + j : c - 1;
            sl[j] = __builtin_nontemporal_load(&s[idx]);
        }
#pragma unroll
        for (int j = 0; j < CH; j++) w[j] = (i + j < c) ? bfhi(sl[j]) : 0.f;
#pragma unroll
        for (int j = 0; j < CH; j++) v[j] = xp[(size_t)(sl[j] & 0xFFFFu) * 16];
#pragma unroll
        for (int j = 0; j < CH; j++) fma8(a0, a1, w[j], v[j]);
    }
    size_t ob = (size_t)node * OUTC4 + out_off4 + 8 * pass + 2 * lane;
    nt_store_f4(&out4[ob], a0);
    nt_store_f4(&out4[ob + 1], a1);
    if (writeb)
        nt_store_u4(&xout[(size_t)node * 16 + 4 * pass + lane],
                    make_uint4(pack2(a0.x, a0.y), pack2(a0.z, a0.w),
                               pack2(a1.x, a1.y), pack2(a1.z, a1.w)));
}

extern "C" void kernel_launch(void* const* d_in, const int* in_sizes, int n_in,
                              void* d_out, int out_size, void* d_ws, size_t ws_size,
                              hipStream_t stream) {
    const float* x = (const float*)d_in[0];
    const int* ei = (const int*)d_in[1];   // int32 per harness convention
    const float* ew = (const float*)d_in[2];
    float* out = (float*)d_out;

    int N = in_sizes[0] / D;
    int E = in_sizes[2];
    const int* row = ei;        // source
    const int* colp = ei + E;   // target

    // ws: [bcur 256 i | gsum 128 f | cnt N i | dinv N f | slots N*CAP u32 |
    //      breg PB*BCAP uint2 | xb0 N*16 uint4 | xb1 ...]
    int* bcur = (int*)d_ws;
    float* gsum = (float*)(bcur + 256);
    int* cnt = (int*)(gsum + 128);
    float* dinv = (float*)(cnt + N);
    unsigned* slots = (unsigned*)(dinv + N);
    uint2* breg = (uint2*)(slots + (size_t)N * CAP);
    uint4* xb0 = (uint4*)(breg + (size_t)PB * BCAP);
    uint4* xb1 = xb0 + (size_t)N * 16;

    hipMemsetAsync(d_ws, 0, 384 * sizeof(int), stream);   // bcur + gsum only

    k_part<<<PB + CB, 256, 0, stream>>>(row, colp, ew, x, bcur, breg, gsum, E, N);

    int GB = (N + 255) / 256;                    // grouping blocks (one per bucket)
    int IB = (N * 16 + 255) / 256;               // init blocks
    k_prep<<<GB + IB, 256, 0, stream>>>(bcur, breg, cnt, dinv, slots, (const float4*)x,
                                        gsum, (float4*)out, xb0, N, GB, 1.f / (float)N);

    // hop1 (fused fp32 norm): xb0 -> out[:,128:256] + xb1
    int pblocks = (N * 16 + 255) / 256;
    k_prop1<<<pblocks, 256, 0, stream>>>(cnt, slots, dinv, xb0, (float4*)out, xb1, N, 32);

    // hops 2,3: 4 column-pass kernels each (L2-resident 3.2MB sub-table)
    int qblocks = (N * 4 + 255) / 256;
    for (int p = 0; p < 4; p++)
        k_pass<<<qblocks, 256, 0, stream>>>(cnt, slots, xb1, (float4*)out, xb0, N, 64, p, 1);
    for (int p = 0; p < 4; p++)
        k_pass<<<qblocks, 256, 0, stream>>>(cnt, slots, xb0, (float4*)out, xb1, N, 96, p, 0);
}

// Round 5
// 332.160 us; speedup vs baseline: 1.2085x; 1.2085x over previous
//
#include <hip/hip_runtime.h>

// SGP spatial encoder: out[n] = concat(x, A x, A^2 x, A^3 x, mean(x)) with
// A = D^-1/2 W D^-1/2 (in-degree at col/target).
// R6: chunk edge loop -> multiple gathers in flight.
// R7/R8 FAILED (cnt padding, atomic MLP) => k_build device-atomic THROUGHPUT
//   bound; R9 bucket partition fixed it (65k atomics): 315->284us.
// R10 FAILED (401us): column-pass split shrank gathers 256B->64B random,
//   losing DRAM burst efficiency. REVERTED. Rule: never shrink gather bursts.
// R11: capture the 16x source-row reuse instead. Sort each node's slot list
// by source (rank-sort in LDS during hop1, which already rewrites slots);
// every hop walks its list in NP=8 source-band passes -> all concurrent waves
// gather from the same ~1.6MB band -> per-XCD-L2-resident -> 15/16 L2 hits.
// Bursts stay 256B, 3 hop launches stay 3. nt stores on output streams.

#define D 128
#define OUTC4 160   // float4s per output row
#define CAP 64      // slots per node; Poisson(16) => overflow ~impossible (guarded)
#define CH 4        // gathers in flight per band chunk
#define NP 8        // source bands per hop (N/8 nodes = 1.6MB table slice)
#define PB 256      // partition blocks = coarse buckets
#define CB 512      // colsum blocks
#define BCAP 5120   // bucket capacity (mean 4096, 16 sigma headroom; guarded)

typedef float f4v __attribute__((ext_vector_type(4)));
typedef unsigned u4v __attribute__((ext_vector_type(4)));

__device__ inline void nt_store_f4(float4* p, float4 v) {
    f4v t = {v.x, v.y, v.z, v.w};
    __builtin_nontemporal_store(t, (f4v*)p);
}
__device__ inline void nt_store_u4(uint4* p, uint4 v) {
    u4v t = {v.x, v.y, v.z, v.w};
    __builtin_nontemporal_store(t, (u4v*)p);
}

__device__ inline unsigned short f2bf(float f) {
    unsigned u = __float_as_uint(f);
    u += 0x7FFFu + ((u >> 16) & 1u);   // round-nearest-even
    return (unsigned short)(u >> 16);
}
__device__ inline float bfhi(unsigned u) {           // bf16 in high half
    return __uint_as_float(u & 0xFFFF0000u);
}
__device__ inline float bflo(unsigned u) {           // bf16 in low half
    return __uint_as_float(u << 16);
}
__device__ inline unsigned pack2(float lo, float hi) {
    return ((unsigned)f2bf(hi) << 16) | (unsigned)f2bf(lo);
}
__device__ inline void fma8(float4& a0, float4& a1, float w, uint4 v) {
    a0.x += w * bflo(v.x); a0.y += w * bfhi(v.x);
    a0.z += w * bflo(v.y); a0.w += w * bfhi(v.y);
    a1.x += w * bflo(v.z); a1.y += w * bfhi(v.z);
    a1.z += w * bflo(v.w); a1.w += w * bfhi(v.w);
}

// blocks [0,PB): partition edges into coarse buckets. blocks [PB,PB+CB): x colsum.
__global__ void k_part(const int* __restrict__ row, const int* __restrict__ col,
                       const float* __restrict__ ew, const float* __restrict__ x,
                       int* __restrict__ bcur, uint2* __restrict__ breg,
                       float* __restrict__ gsum, int E, int N) {
    __shared__ int shi[512];   // [0,256)=hist/cursor, [256,512)=chunk base; colsum aliases float
    if ((int)blockIdx.x < PB) {
        int* hist = shi;
        int* base = shi + 256;
        int rng = (E + PB - 1) / PB;
        int e0 = blockIdx.x * rng;
        int e1 = e0 + rng; if (e1 > E) e1 = E;
        hist[threadIdx.x] = 0;
        __syncthreads();
        for (int e = e0 + (int)threadIdx.x; e < e1; e += 256)
            atomicAdd(&hist[(unsigned)col[e] >> 8], 1);
        __syncthreads();
        int h = hist[threadIdx.x];
        if (h) base[threadIdx.x] = atomicAdd(&bcur[threadIdx.x], h);
        __syncthreads();
        hist[threadIdx.x] = 0;   // reuse as block-local cursor
        __syncthreads();
        for (int e = e0 + (int)threadIdx.x; e < e1; e += 256) {
            int c = col[e];
            int b = (unsigned)c >> 8;
            int r = atomicAdd(&hist[b], 1);
            int pos = base[b] + r;
            if (pos < BCAP)
                breg[(size_t)b * BCAP + pos] =
                    make_uint2(((unsigned)f2bf(ew[e]) << 16) | (unsigned)row[e], (unsigned)c);
        }
    } else {
        float* sh = (float*)shi;
        int bid = blockIdx.x - PB;        // 0..CB-1
        int f = threadIdx.x & 127;
        int sub = threadIdx.x >> 7;       // 0/1
        float acc = 0.f;
        for (int n = bid * 2 + sub; n < N; n += CB * 2)
            acc += x[(size_t)n * D + f];
        if (sub) sh[f] = acc;
        __syncthreads();
        if (!sub) atomicAdd(&gsum[f], acc + sh[f]);
    }
}

// blocks [0,GB): group bucket -> slots, cnt, dinv (LDS atomics only).
// blocks [GB,...): init (x copy / mean broadcast / bf16 staging).
__global__ void k_prep(const int* __restrict__ bcur, const uint2* __restrict__ breg,
                       int* __restrict__ cnt, float* __restrict__ dinv,
                       unsigned* __restrict__ slots, const float4* __restrict__ x4,
                       const float* __restrict__ gsum, float4* __restrict__ out4,
                       uint4* __restrict__ xb0, int N, int GB, float invN) {
    __shared__ int shi[512];   // [0,256)=ncur, [256,512)=wsum(float)
    if ((int)blockIdx.x < GB) {
        int* ncur = shi;
        float* wsum = (float*)(shi + 256);
        int b = blockIdx.x;
        ncur[threadIdx.x] = 0;
        wsum[threadIdx.x] = 0.f;
        __syncthreads();
        int cb = bcur[b]; if (cb > BCAP) cb = BCAP;
        const uint2* br = breg + (size_t)b * BCAP;
        for (int i = threadIdx.x; i < cb; i += 256) {
            uint2 ed = br[i];
            int node = (int)ed.y;
            int l = node & 255;
            int r = atomicAdd(&ncur[l], 1);
            if (r < CAP) slots[(size_t)node * CAP + r] = ed.x;
            atomicAdd(&wsum[l], bfhi(ed.x));
        }
        __syncthreads();
        int node = b * 256 + (int)threadIdx.x;
        if (node < N) {
            cnt[node] = ncur[threadIdx.x];
            float v = wsum[threadIdx.x];
            dinv[node] = v > 0.f ? rsqrtf(v) : 0.f;
        }
    } else {
        int t = (blockIdx.x - GB) * 256 + threadIdx.x;
        if (t >= N * 16) return;
        int n = t >> 4;
        int q = t & 15;
        float4 v0 = x4[(size_t)n * 32 + 2 * q];
        float4 v1 = x4[(size_t)n * 32 + 2 * q + 1];
        size_t ob = (size_t)n * OUTC4;
        nt_store_f4(&out4[ob + 2 * q], v0);
        nt_store_f4(&out4[ob + 2 * q + 1], v1);
        xb0[(size_t)n * 16 + q] = make_uint4(pack2(v0.x, v0.y), pack2(v0.z, v0.w),
                                             pack2(v1.x, v1.y), pack2(v1.z, v1.w));
        int g = 8 * q;
        nt_store_f4(&out4[ob + 128 + 2 * q],
                    make_float4(gsum[g] * invN, gsum[g + 1] * invN,
                                gsum[g + 2] * invN, gsum[g + 3] * invN));
        nt_store_f4(&out4[ob + 129 + 2 * q],
                    make_float4(gsum[g + 4] * invN, gsum[g + 5] * invN,
                                gsum[g + 6] * invN, gsum[g + 7] * invN));
    }
}

// hop kernel: 16 lanes/node, lane owns 8 bf16 columns. Slot list staged in LDS.
// NORM (hop1): rank-sort list by source in LDS; w = dinv[dst]*ew*dinv[src];
// slots rewritten SORTED with bf16(w) -> hops 2,3 read sorted lists for free.
// All hops walk the sorted list in NP source-band passes so concurrent waves
// gather from the same ~N/NP*256B table slice (per-XCD-L2-resident).
template <bool NORM>
__global__ void k_hop(const int* __restrict__ cnt, unsigned* __restrict__ slots,
                      const float* __restrict__ dinv, const uint4* __restrict__ xin,
                      float4* __restrict__ out4, uint4* __restrict__ xout,
                      int N, int out_off4, int writeb) {
    __shared__ unsigned sls[16][65];   // 65 stride: conflict-free rank-sort
    int nid = threadIdx.x >> 4;
    int lane = threadIdx.x & 15;
    int node = blockIdx.x * 16 + nid;
    bool valid = node < N;
    int c = 0;
    unsigned* s = slots;   // safe dummy
    if (valid) {
        c = cnt[node]; if (c > CAP) c = CAP;
        s = slots + (size_t)node * CAP;
        for (int i = lane; i < c; i += 16) sls[nid][i] = s[i];
    }
    __syncthreads();
    if (NORM) {
        // parallel stable rank-sort by source id (low16); 16 lanes, LDS broadcast
        unsigned vals[4]; int rks[4];
#pragma unroll
        for (int k = 0; k < 4; k++) {
            int e = lane + 16 * k;
            rks[k] = -1;
            if (e < c) {
                unsigned v = sls[nid][e];
                unsigned key = v & 0xFFFFu;
                int r = 0;
                for (int f = 0; f < c; f++) {
                    unsigned kf = sls[nid][f] & 0xFFFFu;
                    r += (kf < key) || (kf == key && f < e);
                }
                vals[k] = v; rks[k] = r;
            }
        }
        __syncthreads();
#pragma unroll
        for (int k = 0; k < 4; k++)
            if (rks[k] >= 0) sls[nid][rks[k]] = vals[k];
        __syncthreads();
    }
    float dd = (NORM && valid) ? dinv[node] : 0.f;
    float4 a0 = make_float4(0.f, 0.f, 0.f, 0.f);
    float4 a1 = make_float4(0.f, 0.f, 0.f, 0.f);
    int i = 0;
    for (int p = 1; p <= NP; p++) {
        int lim = (int)(((long long)N * p) / NP);
        int lo = i;
        while (i < c && (int)(sls[nid][i] & 0xFFFFu) < lim) i++;
        for (int q = lo; q < i; q += CH) {   // clamp-tail chunk; dups are L1 hits
            unsigned sl[CH]; float w[CH]; uint4 v[CH];
#pragma unroll
            for (int j = 0; j < CH; j++) {
                int idx = (q + j < i) ? q + j : i - 1;
                sl[j] = sls[nid][idx];
            }
#pragma unroll
            for (int j = 0; j < CH; j++) {
                float ww = NORM ? dd * bfhi(sl[j]) * dinv[sl[j] & 0xFFFFu]
                                : bfhi(sl[j]);
                w[j] = (q + j < i) ? ww : 0.f;
            }
            if (NORM && lane == 0) {
#pragma unroll
                for (int j = 0; j < CH; j++)
                    if (q + j < i)
                        s[q + j] = ((unsigned)f2bf(w[j]) << 16) | (sl[j] & 0xFFFFu);
            }
#pragma unroll
            for (int j = 0; j < CH; j++)
                v[j] = xin[(size_t)(sl[j] & 0xFFFFu) * 16 + lane];
#pragma unroll
            for (int j = 0; j < CH; j++) fma8(a0, a1, w[j], v[j]);
        }
    }
    if (!valid) return;
    size_t ob = (size_t)node * OUTC4 + out_off4 + 2 * lane;
    nt_store_f4(&out4[ob], a0);
    nt_store_f4(&out4[ob + 1], a1);
    if (writeb)
        nt_store_u4(&xout[(size_t)node * 16 + lane],
                    make_uint4(pack2(a0.x, a0.y), pack2(a0.z, a0.w),
                               pack2(a1.x, a1.y), pack2(a1.z, a1.w)));
}

extern "C" void kernel_launch(void* const* d_in, const int* in_sizes, int n_in,
                              void* d_out, int out_size, void* d_ws, size_t ws_size,
                              hipStream_t stream) {
    const float* x = (const float*)d_in[0];
    const int* ei = (const int*)d_in[1];   // int32 per harness convention
    const float* ew = (const float*)d_in[2];
    float* out = (float*)d_out;

    int N = in_sizes[0] / D;
    int E = in_sizes[2];
    const int* row = ei;        // source
    const int* colp = ei + E;   // target

    // ws: [bcur 256 i | gsum 128 f | cnt N i | dinv N f | slots N*CAP u32 |
    //      breg PB*BCAP uint2 | xb0 N*16 uint4 | xb1 ...]
    int* bcur = (int*)d_ws;
    float* gsum = (float*)(bcur + 256);
    int* cnt = (int*)(gsum + 128);
    float* dinv = (float*)(cnt + N);
    unsigned* slots = (unsigned*)(dinv + N);
    uint2* breg = (uint2*)(slots + (size_t)N * CAP);
    uint4* xb0 = (uint4*)(breg + (size_t)PB * BCAP);
    uint4* xb1 = xb0 + (size_t)N * 16;

    hipMemsetAsync(d_ws, 0, 384 * sizeof(int), stream);   // bcur + gsum only

    k_part<<<PB + CB, 256, 0, stream>>>(row, colp, ew, x, bcur, breg, gsum, E, N);

    int GB = (N + 255) / 256;                    // grouping blocks (one per bucket)
    int IB = (N * 16 + 255) / 256;               // init blocks
    k_prep<<<GB + IB, 256, 0, stream>>>(bcur, breg, cnt, dinv, slots, (const float4*)x,
                                        gsum, (float4*)out, xb0, N, GB, 1.f / (float)N);

    int hblocks = (N + 15) / 16;
    // hop1 (sort + fused fp32 norm): xb0 -> out[:,128:256] + xb1
    k_hop<true><<<hblocks, 256, 0, stream>>>(cnt, slots, dinv, xb0, (float4*)out, xb1, N, 32, 1);
    // hop2: xb1 -> out[:,256:384] + xb0
    k_hop<false><<<hblocks, 256, 0, stream>>>(cnt, slots, dinv, xb1, (float4*)out, xb0, N, 64, 1);
    // hop3: xb0 -> out[:,384:512]
    k_hop<false><<<hblocks, 256, 0, stream>>>(cnt, slots, dinv, xb0, (float4*)out, xb1, N, 96, 0);
}

// Round 6
// 321.785 us; speedup vs baseline: 1.2475x; 1.0322x over previous
//
#include <hip/hip_runtime.h>

// SGP spatial encoder: out[n] = concat(x, A x, A^2 x, A^3 x, mean(x)) with
// A = D^-1/2 W D^-1/2 (in-degree at col/target).
// R6: chunk-8 edge loop -> 8 gathers in flight.
// R7/R8 FAILED (cnt padding, atomic MLP) => k_build device-atomic THROUGHPUT
//   bound; R9 bucket partition fixed it (65k atomics): 315->284us.
// R10 FAILED (401us): column-pass split shrank gathers 256B->64B. Reverted.
// R11 FAILED (332us): statistical source-banding desyncs without lockstep;
//   sort + band-walk + CH=4 were pure overhead. Reverted to R9 structure.
// R12: props are latency-capped (~40-line/CU cap x ~480cy avg). Keep R9
// structure; remove L2 write-allocate pollution: nt stores on all streaming
// outputs (out4, xb staging) + nt loads on read-once slot stream. L2 keeps
// the 12.8MB gather table -> higher L2 hit -> lower avg gather latency.

#define D 128
#define OUTC4 160   // float4s per output row
#define CAP 64      // slots per node; Poisson(16) => overflow ~impossible (guarded)
#define CH 8        // edge chunk = gathers in flight per thread (prop)
#define PB 256      // partition blocks = coarse buckets
#define CB 512      // colsum blocks
#define BCAP 5120   // bucket capacity (mean 4096, 16 sigma headroom; guarded)

typedef float f4v __attribute__((ext_vector_type(4)));
typedef unsigned u4v __attribute__((ext_vector_type(4)));

__device__ inline void nt_store_f4(float4* p, float4 v) {
    f4v t = {v.x, v.y, v.z, v.w};
    __builtin_nontemporal_store(t, (f4v*)p);
}
__device__ inline void nt_store_u4(uint4* p, uint4 v) {
    u4v t = {v.x, v.y, v.z, v.w};
    __builtin_nontemporal_store(t, (u4v*)p);
}

__device__ inline unsigned short f2bf(float f) {
    unsigned u = __float_as_uint(f);
    u += 0x7FFFu + ((u >> 16) & 1u);   // round-nearest-even
    return (unsigned short)(u >> 16);
}
__device__ inline float bfhi(unsigned u) {           // bf16 in high half
    return __uint_as_float(u & 0xFFFF0000u);
}
__device__ inline float bflo(unsigned u) {           // bf16 in low half
    return __uint_as_float(u << 16);
}
__device__ inline unsigned pack2(float lo, float hi) {
    return ((unsigned)f2bf(hi) << 16) | (unsigned)f2bf(lo);
}
__device__ inline void fma8(float4& a0, float4& a1, float w, uint4 v) {
    a0.x += w * bflo(v.x); a0.y += w * bfhi(v.x);
    a0.z += w * bflo(v.y); a0.w += w * bfhi(v.y);
    a1.x += w * bflo(v.z); a1.y += w * bfhi(v.z);
    a1.z += w * bflo(v.w); a1.w += w * bfhi(v.w);
}

// blocks [0,PB): partition edges into coarse buckets. blocks [PB,PB+CB): x colsum.
__global__ void k_part(const int* __restrict__ row, const int* __restrict__ col,
                       const float* __restrict__ ew, const float* __restrict__ x,
                       int* __restrict__ bcur, uint2* __restrict__ breg,
                       float* __restrict__ gsum, int E, int N) {
    __shared__ int shi[512];   // [0,256)=hist/cursor, [256,512)=chunk base; colsum aliases float
    if ((int)blockIdx.x < PB) {
        int* hist = shi;
        int* base = shi + 256;
        int rng = (E + PB - 1) / PB;
        int e0 = blockIdx.x * rng;
        int e1 = e0 + rng; if (e1 > E) e1 = E;
        hist[threadIdx.x] = 0;
        __syncthreads();
        for (int e = e0 + (int)threadIdx.x; e < e1; e += 256)
            atomicAdd(&hist[(unsigned)col[e] >> 8], 1);
        __syncthreads();
        int h = hist[threadIdx.x];
        if (h) base[threadIdx.x] = atomicAdd(&bcur[threadIdx.x], h);
        __syncthreads();
        hist[threadIdx.x] = 0;   // reuse as block-local cursor
        __syncthreads();
        for (int e = e0 + (int)threadIdx.x; e < e1; e += 256) {
            int c = col[e];
            int b = (unsigned)c >> 8;
            int r = atomicAdd(&hist[b], 1);
            int pos = base[b] + r;
            if (pos < BCAP)
                breg[(size_t)b * BCAP + pos] =
                    make_uint2(((unsigned)f2bf(ew[e]) << 16) | (unsigned)row[e], (unsigned)c);
        }
    } else {
        float* sh = (float*)shi;
        int bid = blockIdx.x - PB;        // 0..CB-1
        int f = threadIdx.x & 127;
        int sub = threadIdx.x >> 7;       // 0/1
        float acc = 0.f;
        for (int n = bid * 2 + sub; n < N; n += CB * 2)
            acc += x[(size_t)n * D + f];
        if (sub) sh[f] = acc;
        __syncthreads();
        if (!sub) atomicAdd(&gsum[f], acc + sh[f]);
    }
}

// blocks [0,GB): group bucket -> slots, cnt, dinv (LDS atomics only).
// blocks [GB,...): init (x copy / mean broadcast / bf16 staging).
__global__ void k_prep(const int* __restrict__ bcur, const uint2* __restrict__ breg,
                       int* __restrict__ cnt, float* __restrict__ dinv,
                       unsigned* __restrict__ slots, const float4* __restrict__ x4,
                       const float* __restrict__ gsum, float4* __restrict__ out4,
                       uint4* __restrict__ xb0, int N, int GB, float invN) {
    __shared__ int shi[512];   // [0,256)=ncur, [256,512)=wsum(float)
    if ((int)blockIdx.x < GB) {
        int* ncur = shi;
        float* wsum = (float*)(shi + 256);
        int b = blockIdx.x;
        ncur[threadIdx.x] = 0;
        wsum[threadIdx.x] = 0.f;
        __syncthreads();
        int cb = bcur[b]; if (cb > BCAP) cb = BCAP;
        const uint2* br = breg + (size_t)b * BCAP;
        for (int i = threadIdx.x; i < cb; i += 256) {
            uint2 ed = br[i];
            int node = (int)ed.y;
            int l = node & 255;
            int r = atomicAdd(&ncur[l], 1);
            if (r < CAP) slots[(size_t)node * CAP + r] = ed.x;
            atomicAdd(&wsum[l], bfhi(ed.x));
        }
        __syncthreads();
        int node = b * 256 + (int)threadIdx.x;
        if (node < N) {
            cnt[node] = ncur[threadIdx.x];
            float v = wsum[threadIdx.x];
            dinv[node] = v > 0.f ? rsqrtf(v) : 0.f;
        }
    } else {
        int t = (blockIdx.x - GB) * 256 + threadIdx.x;
        if (t >= N * 16) return;
        int n = t >> 4;
        int q = t & 15;
        float4 v0 = x4[(size_t)n * 32 + 2 * q];
        float4 v1 = x4[(size_t)n * 32 + 2 * q + 1];
        size_t ob = (size_t)n * OUTC4;
        nt_store_f4(&out4[ob + 2 * q], v0);
        nt_store_f4(&out4[ob + 2 * q + 1], v1);
        xb0[(size_t)n * 16 + q] = make_uint4(pack2(v0.x, v0.y), pack2(v0.z, v0.w),
                                             pack2(v1.x, v1.y), pack2(v1.z, v1.w));
        int g = 8 * q;
        nt_store_f4(&out4[ob + 128 + 2 * q],
                    make_float4(gsum[g] * invN, gsum[g + 1] * invN,
                                gsum[g + 2] * invN, gsum[g + 3] * invN));
        nt_store_f4(&out4[ob + 129 + 2 * q],
                    make_float4(gsum[g + 4] * invN, gsum[g + 5] * invN,
                                gsum[g + 6] * invN, gsum[g + 7] * invN));
    }
}

// pull hop: 16 lanes/node, lane owns 8 bf16 columns. Chunk-8 edge loop for MLP.
// NORM (hop1): w = dinv[dst]*ew*dinv[src] fp32; slot rewritten as bf16(w).
// Streaming outputs nt; slot stream nt-loaded (read-once). Gathers cached.
template <bool NORM>
__global__ void k_prop(const int* __restrict__ cnt, unsigned* __restrict__ slots,
                       const float* __restrict__ dinv, const uint4* __restrict__ xin,
                       float4* __restrict__ out4, uint4* __restrict__ xout,
                       int N, int out_off4, int writeb) {
    int t = blockIdx.x * blockDim.x + threadIdx.x;
    int node = t >> 4;
    if (node >= N) return;
    int lane = t & 15;
    int c = cnt[node]; if (c > CAP) c = CAP;
    unsigned* s = slots + (size_t)node * CAP;
    float dd = NORM ? dinv[node] : 0.f;
    float4 a0 = make_float4(0.f, 0.f, 0.f, 0.f);
    float4 a1 = make_float4(0.f, 0.f, 0.f, 0.f);
    int i = 0;
    for (; i + CH <= c; i += CH) {
        unsigned sl[CH]; float w[CH]; uint4 v[CH];
#pragma unroll
        for (int j = 0; j < CH; j++) sl[j] = __builtin_nontemporal_load(&s[i + j]);
#pragma unroll
        for (int j = 0; j < CH; j++)
            w[j] = NORM ? dd * bfhi(sl[j]) * dinv[sl[j] & 0xFFFFu] : bfhi(sl[j]);
        if (NORM && lane == 0) {
#pragma unroll
            for (int j = 0; j < CH; j++)
                s[i + j] = ((unsigned)f2bf(w[j]) << 16) | (sl[j] & 0xFFFFu);
        }
#pragma unroll
        for (int j = 0; j < CH; j++) v[j] = xin[(size_t)(sl[j] & 0xFFFFu) * 16 + lane];
#pragma unroll
        for (int j = 0; j < CH; j++) fma8(a0, a1, w[j], v[j]);
    }
    if (i < c) {  // predicated tail chunk; clamped dup addresses are cache-hits
        unsigned sl[CH]; float w[CH]; uint4 v[CH];
#pragma unroll
        for (int j = 0; j < CH; j++) {
            int idx = (i + j < c) ? i + j : c - 1;
            sl[j] = __builtin_nontemporal_load(&s[idx]);
        }
#pragma unroll
        for (int j = 0; j < CH; j++) {
            float ww = NORM ? dd * bfhi(sl[j]) * dinv[sl[j] & 0xFFFFu] : bfhi(sl[j]);
            w[j] = (i + j < c) ? ww : 0.f;
        }
        if (NORM && lane == 0) {
#pragma unroll
            for (int j = 0; j < CH; j++)
                if (i + j < c) s[i + j] = ((unsigned)f2bf(w[j]) << 16) | (sl[j] & 0xFFFFu);
        }
#pragma unroll
        for (int j = 0; j < CH; j++) v[j] = xin[(size_t)(sl[j] & 0xFFFFu) * 16 + lane];
#pragma unroll
        for (int j = 0; j < CH; j++) fma8(a0, a1, w[j], v[j]);
    }
    size_t ob = (size_t)node * OUTC4 + out_off4 + 2 * lane;
    nt_store_f4(&out4[ob], a0);
    nt_store_f4(&out4[ob + 1], a1);
    if (writeb)
        nt_store_u4(&xout[(size_t)node * 16 + lane],
                    make_uint4(pack2(a0.x, a0.y), pack2(a0.z, a0.w),
                               pack2(a1.x, a1.y), pack2(a1.z, a1.w)));
}

extern "C" void kernel_launch(void* const* d_in, const int* in_sizes, int n_in,
                              void* d_out, int out_size, void* d_ws, size_t ws_size,
                              hipStream_t stream) {
    const float* x = (const float*)d_in[0];
    const int* ei = (const int*)d_in[1];   // int32 per harness convention
    const float* ew = (const float*)d_in[2];
    float* out = (float*)d_out;

    int N = in_sizes[0] / D;
    int E = in_sizes[2];
    const int* row = ei;        // source
    const int* colp = ei + E;   // target

    // ws: [bcur 256 i | gsum 128 f | cnt N i | dinv N f | slots N*CAP u32 |
    //      breg PB*BCAP uint2 | xb0 N*16 uint4 | xb1 ...]
    int* bcur = (int*)d_ws;
    float* gsum = (float*)(bcur + 256);
    int* cnt = (int*)(gsum + 128);
    float* dinv = (float*)(cnt + N);
    unsigned* slots = (unsigned*)(dinv + N);
    uint2* breg = (uint2*)(slots + (size_t)N * CAP);
    uint4* xb0 = (uint4*)(breg + (size_t)PB * BCAP);
    uint4* xb1 = xb0 + (size_t)N * 16;

    hipMemsetAsync(d_ws, 0, 384 * sizeof(int), stream);   // bcur + gsum only

    k_part<<<PB + CB, 256, 0, stream>>>(row, colp, ew, x, bcur, breg, gsum, E, N);

    int GB = (N + 255) / 256;                    // grouping blocks (one per bucket)
    int IB = (N * 16 + 255) / 256;               // init blocks
    k_prep<<<GB + IB, 256, 0, stream>>>(bcur, breg, cnt, dinv, slots, (const float4*)x,
                                        gsum, (float4*)out, xb0, N, GB, 1.f / (float)N);

    int pblocks = (N * 16 + 255) / 256;
    // hop1 (fused norm): xb0 -> out[:,128:256] + xb1
    k_prop<true><<<pblocks, 256, 0, stream>>>(cnt, slots, dinv, xb0, (float4*)out, xb1, N, 32, 1);
    // hop2: xb1 -> out[:,256:384] + xb0
    k_prop<false><<<pblocks, 256, 0, stream>>>(cnt, slots, dinv, xb1, (float4*)out, xb0, N, 64, 1);
    // hop3: xb0 -> out[:,384:512]
    k_prop<false><<<pblocks, 256, 0, stream>>>(cnt, slots, dinv, xb0, (float4*)out, xb1, N, 96, 0);
}

// Round 7
// 282.548 us; speedup vs baseline: 1.4207x; 1.1389x over previous
//
#include <hip/hip_runtime.h>

// SGP spatial encoder: out[n] = concat(x, A x, A^2 x, A^3 x, mean(x)) with
// A = D^-1/2 W D^-1/2 (in-degree at col/target).
// R6: chunk-8 edge loop -> 8 gathers in flight.
// R7/R8 FAILED (cnt padding, atomic MLP) => k_build device-atomic THROUGHPUT
//   bound; R9 bucket partition fixed it (65k atomics): 315->284us. BEST.
// R10 FAILED (401us): column-pass split shrank gathers 256B->64B. Reverted.
// R11 FAILED (332us): statistical source-banding desyncs without lockstep.
// R12 FAILED (322us): nt loads on slots stole MSHR entries from gathers
//   (16-lane broadcast reads are L1-friendly; nt forced misses); nt stores
//   bypassed L2 write-combining. Reverted.
// Props are pinned by outstanding-line cap (~40/CU) x L3 latency on a 12.8MB
// table (>4MB per-XCD L2; bf16 is the precision floor at 2^-7 tolerance).
// This is the R9 structure, reverted exactly.

#define D 128
#define OUTC4 160   // float4s per output row
#define CAP 64      // slots per node; Poisson(16) => overflow ~impossible (guarded)
#define CH 8        // edge chunk = gathers in flight per thread (prop)
#define PB 256      // partition blocks = coarse buckets
#define CB 512      // colsum blocks
#define BCAP 5120   // bucket capacity (mean 4096, 16 sigma headroom; guarded)

__device__ inline unsigned short f2bf(float f) {
    unsigned u = __float_as_uint(f);
    u += 0x7FFFu + ((u >> 16) & 1u);   // round-nearest-even
    return (unsigned short)(u >> 16);
}
__device__ inline float bfhi(unsigned u) {           // bf16 in high half
    return __uint_as_float(u & 0xFFFF0000u);
}
__device__ inline float bflo(unsigned u) {           // bf16 in low half
    return __uint_as_float(u << 16);
}
__device__ inline unsigned pack2(float lo, float hi) {
    return ((unsigned)f2bf(hi) << 16) | (unsigned)f2bf(lo);
}
__device__ inline void fma8(float4& a0, float4& a1, float w, uint4 v) {
    a0.x += w * bflo(v.x); a0.y += w * bfhi(v.x);
    a0.z += w * bflo(v.y); a0.w += w * bfhi(v.y);
    a1.x += w * bflo(v.z); a1.y += w * bfhi(v.z);
    a1.z += w * bflo(v.w); a1.w += w * bfhi(v.w);
}

// blocks [0,PB): partition edges into coarse buckets. blocks [PB,PB+CB): x colsum.
__global__ void k_part(const int* __restrict__ row, const int* __restrict__ col,
                       const float* __restrict__ ew, const float* __restrict__ x,
                       int* __restrict__ bcur, uint2* __restrict__ breg,
                       float* __restrict__ gsum, int E, int N) {
    __shared__ int shi[512];   // [0,256)=hist/cursor, [256,512)=chunk base; colsum aliases float
    if ((int)blockIdx.x < PB) {
        int* hist = shi;
        int* base = shi + 256;
        int rng = (E + PB - 1) / PB;
        int e0 = blockIdx.x * rng;
        int e1 = e0 + rng; if (e1 > E) e1 = E;
        hist[threadIdx.x] = 0;
        __syncthreads();
        for (int e = e0 + (int)threadIdx.x; e < e1; e += 256)
            atomicAdd(&hist[(unsigned)col[e] >> 8], 1);
        __syncthreads();
        int h = hist[threadIdx.x];
        if (h) base[threadIdx.x] = atomicAdd(&bcur[threadIdx.x], h);
        __syncthreads();
        hist[threadIdx.x] = 0;   // reuse as block-local cursor
        __syncthreads();
        for (int e = e0 + (int)threadIdx.x; e < e1; e += 256) {
            int c = col[e];
            int b = (unsigned)c >> 8;
            int r = atomicAdd(&hist[b], 1);
            int pos = base[b] + r;
            if (pos < BCAP)
                breg[(size_t)b * BCAP + pos] =
                    make_uint2(((unsigned)f2bf(ew[e]) << 16) | (unsigned)row[e], (unsigned)c);
        }
    } else {
        float* sh = (float*)shi;
        int bid = blockIdx.x - PB;        // 0..CB-1
        int f = threadIdx.x & 127;
        int sub = threadIdx.x >> 7;       // 0/1
        float acc = 0.f;
        for (int n = bid * 2 + sub; n < N; n += CB * 2)
            acc += x[(size_t)n * D + f];
        if (sub) sh[f] = acc;
        __syncthreads();
        if (!sub) atomicAdd(&gsum[f], acc + sh[f]);
    }
}

// blocks [0,GB): group bucket -> slots, cnt, dinv (LDS atomics only).
// blocks [GB,...): init (x copy / mean broadcast / bf16 staging).
__global__ void k_prep(const int* __restrict__ bcur, const uint2* __restrict__ breg,
                       int* __restrict__ cnt, float* __restrict__ dinv,
                       unsigned* __restrict__ slots, const float4* __restrict__ x4,
                       const float* __restrict__ gsum, float4* __restrict__ out4,
                       uint4* __restrict__ xb0, int N, int GB, float invN) {
    __shared__ int shi[512];   // [0,256)=ncur, [256,512)=wsum(float)
    if ((int)blockIdx.x < GB) {
        int* ncur = shi;
        float* wsum = (float*)(shi + 256);
        int b = blockIdx.x;
        ncur[threadIdx.x] = 0;
        wsum[threadIdx.x] = 0.f;
        __syncthreads();
        int cb = bcur[b]; if (cb > BCAP) cb = BCAP;
        const uint2* br = breg + (size_t)b * BCAP;
        for (int i = threadIdx.x; i < cb; i += 256) {
            uint2 ed = br[i];
            int node = (int)ed.y;
            int l = node & 255;
            int r = atomicAdd(&ncur[l], 1);
            if (r < CAP) slots[(size_t)node * CAP + r] = ed.x;
            atomicAdd(&wsum[l], bfhi(ed.x));
        }
        __syncthreads();
        int node = b * 256 + (int)threadIdx.x;
        if (node < N) {
            cnt[node] = ncur[threadIdx.x];
            float v = wsum[threadIdx.x];
            dinv[node] = v > 0.f ? rsqrtf(v) : 0.f;
        }
    } else {
        int t = (blockIdx.x - GB) * 256 + threadIdx.x;
        if (t >= N * 16) return;
        int n = t >> 4;
        int q = t & 15;
        float4 v0 = x4[(size_t)n * 32 + 2 * q];
        float4 v1 = x4[(size_t)n * 32 + 2 * q + 1];
        size_t ob = (size_t)n * OUTC4;
        out4[ob + 2 * q] = v0;
        out4[ob + 2 * q + 1] = v1;
        xb0[(size_t)n * 16 + q] = make_uint4(pack2(v0.x, v0.y), pack2(v0.z, v0.w),
                                             pack2(v1.x, v1.y), pack2(v1.z, v1.w));
        int g = 8 * q;
        out4[ob + 128 + 2 * q] = make_float4(gsum[g] * invN, gsum[g + 1] * invN,
                                             gsum[g + 2] * invN, gsum[g + 3] * invN);
        out4[ob + 129 + 2 * q] = make_float4(gsum[g + 4] * invN, gsum[g + 5] * invN,
                                             gsum[g + 6] * invN, gsum[g + 7] * invN);
    }
}

// pull hop: 16 lanes/node, lane owns 8 bf16 columns. Chunk-8 edge loop for MLP.
// NORM (hop1): w = dinv[dst]*ew*dinv[src] fp32; slot rewritten as bf16(w).
template <bool NORM>
__global__ void k_prop(const int* __restrict__ cnt, unsigned* __restrict__ slots,
                       const float* __restrict__ dinv, const uint4* __restrict__ xin,
                       float4* __restrict__ out4, uint4* __restrict__ xout,
                       int N, int out_off4, int writeb) {
    int t = blockIdx.x * blockDim.x + threadIdx.x;
    int node = t >> 4;
    if (node >= N) return;
    int lane = t & 15;
    int c = cnt[node]; if (c > CAP) c = CAP;
    unsigned* s = slots + (size_t)node * CAP;
    float dd = NORM ? dinv[node] : 0.f;
    float4 a0 = make_float4(0.f, 0.f, 0.f, 0.f);
    float4 a1 = make_float4(0.f, 0.f, 0.f, 0.f);
    int i = 0;
    for (; i + CH <= c; i += CH) {
        unsigned sl[CH]; float w[CH]; uint4 v[CH];
#pragma unroll
        for (int j = 0; j < CH; j++) sl[j] = s[i + j];
#pragma unroll
        for (int j = 0; j < CH; j++)
            w[j] = NORM ? dd * bfhi(sl[j]) * dinv[sl[j] & 0xFFFFu] : bfhi(sl[j]);
        if (NORM && lane == 0) {
#pragma unroll
            for (int j = 0; j < CH; j++)
                s[i + j] = ((unsigned)f2bf(w[j]) << 16) | (sl[j] & 0xFFFFu);
        }
#pragma unroll
        for (int j = 0; j < CH; j++) v[j] = xin[(size_t)(sl[j] & 0xFFFFu) * 16 + lane];
#pragma unroll
        for (int j = 0; j < CH; j++) fma8(a0, a1, w[j], v[j]);
    }
    if (i < c) {  // predicated tail chunk; clamped dup addresses are cache-hits
        unsigned sl[CH]; float w[CH]; uint4 v[CH];
#pragma unroll
        for (int j = 0; j < CH; j++) {
            int idx = (i + j < c) ? i + j : c - 1;
            sl[j] = s[idx];
        }
#pragma unroll
        for (int j = 0; j < CH; j++) {
            float ww = NORM ? dd * bfhi(sl[j]) * dinv[sl[j] & 0xFFFFu] : bfhi(sl[j]);
            w[j] = (i + j < c) ? ww : 0.f;
        }
        if (NORM && lane == 0) {
#pragma unroll
            for (int j = 0; j < CH; j++)
                if (i + j < c) s[i + j] = ((unsigned)f2bf(w[j]) << 16) | (sl[j] & 0xFFFFu);
        }
#pragma unroll
        for (int j = 0; j < CH; j++) v[j] = xin[(size_t)(sl[j] & 0xFFFFu) * 16 + lane];
#pragma unroll
        for (int j = 0; j < CH; j++) fma8(a0, a1, w[j], v[j]);
    }
    size_t ob = (size_t)node * OUTC4 + out_off4 + 2 * lane;
    out4[ob] = a0;
    out4[ob + 1] = a1;
    if (writeb)
        xout[(size_t)node * 16 + lane] =
            make_uint4(pack2(a0.x, a0.y), pack2(a0.z, a0.w),
                       pack2(a1.x, a1.y), pack2(a1.z, a1.w));
}

extern "C" void kernel_launch(void* const* d_in, const int* in_sizes, int n_in,
                              void* d_out, int out_size, void* d_ws, size_t ws_size,
                              hipStream_t stream) {
    const float* x = (const float*)d_in[0];
    const int* ei = (const int*)d_in[1];   // int32 per harness convention
    const float* ew = (const float*)d_in[2];
    float* out = (float*)d_out;

    int N = in_sizes[0] / D;
    int E = in_sizes[2];
    const int* row = ei;        // source
    const int* colp = ei + E;   // target

    // ws: [bcur 256 i | gsum 128 f | cnt N i | dinv N f | slots N*CAP u32 |
    //      breg PB*BCAP uint2 | xb0 N*16 uint4 | xb1 ...]
    int* bcur = (int*)d_ws;
    float* gsum = (float*)(bcur + 256);
    int* cnt = (int*)(gsum + 128);
    float* dinv = (float*)(cnt + N);
    unsigned* slots = (unsigned*)(dinv + N);
    uint2* breg = (uint2*)(slots + (size_t)N * CAP);
    uint4* xb0 = (uint4*)(breg + (size_t)PB * BCAP);
    uint4* xb1 = xb0 + (size_t)N * 16;

    hipMemsetAsync(d_ws, 0, 384 * sizeof(int), stream);   // bcur + gsum only

    k_part<<<PB + CB, 256, 0, stream>>>(row, colp, ew, x, bcur, breg, gsum, E, N);

    int GB = (N + 255) / 256;                    // grouping blocks (one per bucket)
    int IB = (N * 16 + 255) / 256;               // init blocks
    k_prep<<<GB + IB, 256, 0, stream>>>(bcur, breg, cnt, dinv, slots, (const float4*)x,
                                        gsum, (float4*)out, xb0, N, GB, 1.f / (float)N);

    int pblocks = (N * 16 + 255) / 256;
    // hop1 (fused norm): xb0 -> out[:,128:256] + xb1
    k_prop<true><<<pblocks, 256, 0, stream>>>(cnt, slots, dinv, xb0, (float4*)out, xb1, N, 32, 1);
    // hop2: xb1 -> out[:,256:384] + xb0
    k_prop<false><<<pblocks, 256, 0, stream>>>(cnt, slots, dinv, xb1, (float4*)out, xb0, N, 64, 1);
    // hop3: xb0 -> out[:,384:512]
    k_prop<false><<<pblocks, 256, 0, stream>>>(cnt, slots, dinv, xb0, (float4*)out, xb1, N, 96, 0);
}